// Round 5
// baseline (99.680 us; speedup 1.0000x reference)
//
#include <hip/hip_runtime.h>
#include <hip/hip_bf16.h>
#include <math.h>

// Stickbreaking attention via bf16 MFMA, flash-style suffix-scan carry.
// B=2 H=16 S=1024 D=64.
// Round-9 == round-8 with the compile fix: __exp2f (host-only) ->
// __builtin_amdgcn_exp2f (raw v_exp_f32, which IS exp2 on gfx950).
// Round-8 changes vs round-7 (97.3us total; kernel+launch ~8.3us over the
// ~89us fixed harness poison fills):
//  * K staging + Q fragment hi/lo split by TRUNCATION instead of RNE+sub+RNE:
//      hi = x.bits >> 16 ; rem = x - bf16f(hi)  (exact: same exponent)
//      lo = rem.bits >> 16
//    4 VALU/element vs ~7. hi+lo still carries 16 mantissa bits (<2^-16 rel
//    error vs 2^-17 for the RNE pair) -- sub-dominant to the bf16 W/V
//    quantization floor that sets absmax. V staging stays RNE (direct factor).
//  * exp folded to exp2: e = exp2(Sacc * (0.125*log2e)) -- one constant mul
//    replaces scale-mul + exp's internal log2e premul. Sentinel -1e30 and the
//    fmin overflow guard work identically in exp2 domain.
//  * s_setprio(1) around GEMM1/GEMM2 MFMA clusters (T5): two co-resident
//    blocks sit at different iteration phases -> wave role diversity exists,
//    scheduler can favor the MFMA-entering wave.
// Everything else identical to round-7 (product-space scan, 1 barrier/iter
// lgkm-only, K/V LDS double-buffered, register prefetch across the barrier).
// GEMM1 split-precision bf16 (hi+lo residual, 3 MFMAs -> fp32-accurate logits);
// GEMM2 plain bf16. mfma_f32_16x16x32_bf16 layouts per m89/m120:
//   A[m=lane&15][k=(lane>>4)*8+e], B[k][n=lane&15], C/D col=lane&15, row=(lane>>4)*4+reg.

typedef __attribute__((ext_vector_type(8))) short short8;
typedef __attribute__((ext_vector_type(4))) short short4v;
typedef __attribute__((ext_vector_type(4))) float f32x4;

#define PITCH 72   // bf16 elems per LDS row: 144 B, 16B-aligned, bank-uniform for b128

__device__ inline short bf16r(float x) {
    __hip_bfloat16 h = __float2bfloat16(x);   // RNE
    return *(short*)&h;
}
__device__ inline float bf16f(short s) {
    union { unsigned u; float f; } c;
    c.u = ((unsigned)(unsigned short)s) << 16;
    return c.f;
}
// truncation hi/lo split: hi+lo captures 16 mantissa bits, rem exact
__device__ inline void tsplit(float x, short &hi, short &lo) {
    union { float f; unsigned u; } c; c.f = x;
    hi = (short)(c.u >> 16);
    union { unsigned u; float f; } h; h.u = c.u & 0xFFFF0000u;
    union { float f; unsigned u; } r; r.f = x - h.f;
    lo = (short)(r.u >> 16);
}

// Wave-visibility barrier: LDS writes drained (lgkmcnt), but global loads
// (private dest regs) intentionally left in flight -- no vmcnt drain.
__device__ inline void lds_barrier() {
    __builtin_amdgcn_sched_barrier(0);
    asm volatile("s_waitcnt lgkmcnt(0)" ::: "memory");
    __builtin_amdgcn_s_barrier();
    __builtin_amdgcn_sched_barrier(0);
}

__global__ __launch_bounds__(256, 2) void stickbreak_mfma(
    const float* __restrict__ Qg, const float* __restrict__ Kg,
    const float* __restrict__ Vg, float* __restrict__ Og)
{
    __shared__ __align__(16) short Kh[2][64 * PITCH];
    __shared__ __align__(16) short Kl[2][64 * PITCH];
    __shared__ __align__(16) short Vt[2][64 * PITCH];   // V transposed: Vt[d][j]
    __shared__ __align__(16) short Ws[64 * PITCH];      // W strip, [i][j] (intra-wave use)

    const int t = threadIdx.x;
    const int n = blockIdx.x;                 // 0..511
    // n&7 fastest -> all 16 q-tiles of one head share an XCD slot (K/V L2 reuse).
    const int bh = (n & 7) + 8 * (n >> 7);    // 0..31
    const int qr = (n >> 3) & 15;
    const int qt = (n >> 8) ? (15 - qr) : qr; // complementary pairing c <-> c+256

    const size_t hbase = (size_t)bh * 1024 * 64;
    const float* qp = Qg + hbase + (size_t)qt * 64 * 64;
    const float* kp = Kg + hbase;
    const float* vp = Vg + hbase;
    float*       op = Og + hbase + (size_t)qt * 64 * 64;

    const int lane = t & 63;
    const int wv   = t >> 6;      // wave 0..3 -> q-rows [16wv, 16wv+16)
    const int l16  = lane & 15;
    const int q4   = lane >> 4;   // quad 0..3

    // staging maps (K: 16 floats/thread; V transpose: 4x4 register block)
    const int srow = t >> 2;            // 0..63
    const int scol = (t & 3) << 4;      // 0/16/32/48
    const int vj   = (t & 15) << 2;
    const int vd   = (t >> 4) << 2;

    // ---- Q fragments straight to registers (loop-invariant) ----
    short8 qfh[2], qfl[2];
    {
        const float* qrow = qp + (16 * wv + l16) * 64;
        #pragma unroll
        for (int ks = 0; ks < 2; ++ks) {
            const int base = 32 * ks + 8 * q4;
            const float4 f0 = *(const float4*)(qrow + base);
            const float4 f1 = *(const float4*)(qrow + base + 4);
            float a[8] = {f0.x, f0.y, f0.z, f0.w, f1.x, f1.y, f1.z, f1.w};
            #pragma unroll
            for (int j = 0; j < 8; ++j) {
                short hi, lo;
                tsplit(a[j], hi, lo);
                qfh[ks][j] = hi;
                qfl[ks][j] = lo;
            }
        }
    }

    f32x4 Oacc[4];
    #pragma unroll
    for (int i = 0; i < 4; ++i) Oacc[i] = (f32x4){0.f, 0.f, 0.f, 0.f};
    float Prow = 1.f;    // carried suffix PRODUCT for row 16wv+l16 (replicated over q4)

    float4 kreg[4], vreg[4];

    // issue global loads for K/V tile tt into kreg/vreg (non-blocking)
    auto prefetch_tile = [&](int tt) {
        const float* ksrc = kp + (size_t)tt * 4096 + srow * 64 + scol;
        const float* vsrc = vp + (size_t)tt * 4096;
        #pragma unroll
        for (int i = 0; i < 4; ++i) kreg[i] = *(const float4*)(ksrc + 4 * i);
        #pragma unroll
        for (int r = 0; r < 4; ++r) vreg[r] = *(const float4*)(vsrc + (vj + r) * 64 + vd);
    };

    // convert kreg/vreg and store into LDS buffer nb
    auto stage_tile = [&](int nb) {
        short8 h0, h1, l0, l1;
        #pragma unroll
        for (int i = 0; i < 4; ++i) {
            float a[4] = {kreg[i].x, kreg[i].y, kreg[i].z, kreg[i].w};
            #pragma unroll
            for (int j = 0; j < 4; ++j) {
                short hi, lo;
                tsplit(a[j], hi, lo);
                const int idx = 4 * i + j;
                if (idx < 8) { h0[idx] = hi; l0[idx] = lo; }
                else         { h1[idx - 8] = hi; l1[idx - 8] = lo; }
            }
        }
        *(short8*)&Kh[nb][srow * PITCH + scol]     = h0;
        *(short8*)&Kh[nb][srow * PITCH + scol + 8] = h1;
        *(short8*)&Kl[nb][srow * PITCH + scol]     = l0;
        *(short8*)&Kl[nb][srow * PITCH + scol + 8] = l1;
        #pragma unroll
        for (int x = 0; x < 4; ++x) {
            float rr[4] = { x == 0 ? vreg[0].x : x == 1 ? vreg[0].y : x == 2 ? vreg[0].z : vreg[0].w,
                            x == 0 ? vreg[1].x : x == 1 ? vreg[1].y : x == 2 ? vreg[1].z : vreg[1].w,
                            x == 0 ? vreg[2].x : x == 1 ? vreg[2].y : x == 2 ? vreg[2].z : vreg[2].w,
                            x == 0 ? vreg[3].x : x == 1 ? vreg[3].y : x == 2 ? vreg[3].z : vreg[3].w };
            short4v w4;
            #pragma unroll
            for (int r = 0; r < 4; ++r) w4[r] = bf16r(rr[r]);   // V stays RNE
            *(short4v*)&Vt[nb][(vd + x) * PITCH + vj] = w4;
        }
    };

    // ---- prologue: load + stage tile qt into buf 0, start prefetch of qt-1 ----
    prefetch_tile(qt);
    stage_tile(0);
    if (qt > 0) prefetch_tile(qt - 1);
    lds_barrier();

    for (int kt = qt; kt >= 0; --kt) {
        const int cur = (qt - kt) & 1;

        // ---- GEMM1: S^T = K Q^T (split precision, 3 MFMAs per frag pair) ----
        // D[m=j][n=i]: col i = l16, row j = 16nt + 4q4 + reg.
        f32x4 Sacc[4];
        #pragma unroll
        for (int i = 0; i < 4; ++i) Sacc[i] = (f32x4){0.f, 0.f, 0.f, 0.f};
        __builtin_amdgcn_s_setprio(1);
        #pragma unroll
        for (int ks = 0; ks < 2; ++ks) {
            #pragma unroll
            for (int nt = 0; nt < 4; ++nt) {
                const short8 ah = *(const short8*)&Kh[cur][(16 * nt + l16) * PITCH + 32 * ks + 8 * q4];
                const short8 al = *(const short8*)&Kl[cur][(16 * nt + l16) * PITCH + 32 * ks + 8 * q4];
                Sacc[nt] = __builtin_amdgcn_mfma_f32_16x16x32_bf16(ah, qfh[ks], Sacc[nt], 0, 0, 0);
                Sacc[nt] = __builtin_amdgcn_mfma_f32_16x16x32_bf16(al, qfh[ks], Sacc[nt], 0, 0, 0);
                Sacc[nt] = __builtin_amdgcn_mfma_f32_16x16x32_bf16(ah, qfl[ks], Sacc[nt], 0, 0, 0);
            }
        }
        __builtin_amdgcn_s_setprio(0);

        // ---- elementwise + suffix scan, PRODUCT space ----
        // lane owns row i=16wv+l16, j = 16nt+4q4+reg.
        //   e = exp2(l*C) = exp(l/8); b = rcp(1+e) = sigmoid(-l); z = e*b = sigmoid(l)
        //   w[j] = z_j * prod_{j'=j..i} b_j'   (inclusive; b_j appears twice, as in ref)
        const bool diag = (kt == qt);
        const int irow = 16 * wv + l16;          // row within 64-row q-tile
        const float C = 0.180336880f;            // 0.125 * log2(e)
        float zp[4][4];                          // z * in-run inclusive suffix product
        float sR[4];                             // run total products
        #pragma unroll
        for (int nt = 0; nt < 4; ++nt) {
            float b[4], zz[4];
            #pragma unroll
            for (int reg = 0; reg < 4; ++reg) {
                float l2 = Sacc[nt][reg] * C;
                if (diag && (16 * nt + 4 * q4 + reg > irow)) l2 = -1e30f;  // mask sentinel
                l2 = fminf(l2, 80.f);                     // exp2 overflow guard (inf*0=NaN)
                const float e  = __builtin_amdgcn_exp2f(l2);
                const float bb = __builtin_amdgcn_rcpf(1.f + e);
                b[reg] = bb;
                zz[reg] = e * bb;
            }
            const float p3 = b[3];
            const float p2 = b[2] * p3;
            const float p1 = b[1] * p2;
            const float p0 = b[0] * p1;          // inclusive suffix product within run
            zp[nt][0] = zz[0] * p0;
            zp[nt][1] = zz[1] * p1;
            zp[nt][2] = zz[2] * p2;
            zp[nt][3] = zz[3] * p3;
            sR[nt] = p0;
        }
        // cross-lane inclusive suffix PRODUCT over q4 (stride-16 lanes), then over nt
        float ex4[4], Tn[4];
        #pragma unroll
        for (int nt = 0; nt < 4; ++nt) {
            float g = sR[nt];
            float u = __shfl_down(g, 16, 64); if (q4 < 3) g *= u;
            u = __shfl_down(g, 32, 64);       if (q4 < 2) g *= u;
            const float x = __shfl_down(g, 16, 64);   // inclusive product at q4+1
            ex4[nt] = (q4 == 3) ? 1.f : x;            // exclusive: prod over q4' > q4
            Tn[nt]  = __shfl(g, l16, 64);             // nt total (from q4=0 lane of same i)
        }
        const float TSa[4] = { Tn[1] * Tn[2] * Tn[3], Tn[2] * Tn[3], Tn[3], 1.f };
        #pragma unroll
        for (int nt = 0; nt < 4; ++nt) {
            const float cross = ex4[nt] * TSa[nt] * Prow;
            short4v w4;
            #pragma unroll
            for (int reg = 0; reg < 4; ++reg)
                w4[reg] = bf16r(zp[nt][reg] * cross);
            *(short4v*)&Ws[irow * PITCH + 16 * nt + 4 * q4] = w4;
        }
        Prow *= TSa[0] * Tn[0];

        // ---- GEMM2: O += W V  (Ws rows are wave-local; compiler inserts the
        //      lgkmcnt wait for the intra-wave LDS RAW -- no barrier needed) ----
        __builtin_amdgcn_s_setprio(1);
        #pragma unroll
        for (int ks = 0; ks < 2; ++ks) {
            const short8 wa = *(const short8*)&Ws[(16 * wv + l16) * PITCH + 32 * ks + 8 * q4];
            #pragma unroll
            for (int dt = 0; dt < 4; ++dt) {
                const short8 vb = *(const short8*)&Vt[cur][(16 * dt + l16) * PITCH + 32 * ks + 8 * q4];
                Oacc[dt] = __builtin_amdgcn_mfma_f32_16x16x32_bf16(wa, vb, Oacc[dt], 0, 0, 0);
            }
        }
        __builtin_amdgcn_s_setprio(0);

        // ---- stage next tile into the other buffer, prefetch the one after ----
        if (kt > 0) {
            stage_tile(cur ^ 1);                 // consumes kreg/vreg (tile kt-1)
            if (kt > 1) prefetch_tile(kt - 2);   // loads fly across the barrier
            lds_barrier();                       // lgkm only: staging visible, reads drained
        }
    }

    // ---- epilogue: C-layout scatter to global (fp32) ----
    #pragma unroll
    for (int dt = 0; dt < 4; ++dt)
        #pragma unroll
        for (int r = 0; r < 4; ++r)
            op[(16 * wv + 4 * q4 + r) * 64 + 16 * dt + l16] = Oacc[dt][r];
}

extern "C" void kernel_launch(void* const* d_in, const int* in_sizes, int n_in,
                              void* d_out, int out_size, void* d_ws, size_t ws_size,
                              hipStream_t stream) {
    const float* q = (const float*)d_in[0];
    const float* k = (const float*)d_in[1];
    const float* v = (const float*)d_in[2];
    float* out = (float*)d_out;
    stickbreak_mfma<<<dim3(512), dim3(256), 0, stream>>>(q, k, v, out);
}

// Round 6
// 96.444 us; speedup vs baseline: 1.0336x; 1.0336x over previous
//
#include <hip/hip_runtime.h>
#include <hip/hip_bf16.h>
#include <math.h>

// Stickbreaking attention via bf16 MFMA, flash-style suffix-scan carry.
// B=2 H=16 S=1024 D=64.
// Round-10 == round-9 MINUS s_setprio (A/B isolation). Round-9 bundled
// {tsplit, exp2-fold, setprio} and regressed 97.3 -> 99.7us. tsplit/exp2
// strictly remove VALU ops; setprio is the only component with a known
// hurt-mode (m190: GEMM -14TF): with 2 blocks/CU, boosting MFMA waves
// deprioritizes the partner block's staging/prefetch waves -> serializes
// its next iteration on this latency-bound kernel. Removing it.
//  * K staging + Q fragment hi/lo split by TRUNCATION (4 VALU/elem vs ~7);
//    hi+lo carries 16 mantissa bits, sub-dominant to bf16 W/V floor.
//  * e = exp2(Sacc * 0.125*log2e) via __builtin_amdgcn_exp2f (v_exp_f32).
//  * Product-space scan: b=rcp(1+e), z=e*b, suffix products, carry Prow.
//  * 1 barrier/iter (lgkm-only, no vmcnt drain), K/V LDS double-buffered,
//    register prefetch in flight across the barrier.
// GEMM1 split-precision bf16 (hi+lo residual, 3 MFMAs -> fp32-accurate logits);
// GEMM2 plain bf16. mfma_f32_16x16x32_bf16 layouts per m89/m120:
//   A[m=lane&15][k=(lane>>4)*8+e], B[k][n=lane&15], C/D col=lane&15, row=(lane>>4)*4+reg.

typedef __attribute__((ext_vector_type(8))) short short8;
typedef __attribute__((ext_vector_type(4))) short short4v;
typedef __attribute__((ext_vector_type(4))) float f32x4;

#define PITCH 72   // bf16 elems per LDS row: 144 B, 16B-aligned, bank-uniform for b128

__device__ inline short bf16r(float x) {
    __hip_bfloat16 h = __float2bfloat16(x);   // RNE
    return *(short*)&h;
}
__device__ inline float bf16f(short s) {
    union { unsigned u; float f; } c;
    c.u = ((unsigned)(unsigned short)s) << 16;
    return c.f;
}
// truncation hi/lo split: hi+lo captures 16 mantissa bits, rem exact
__device__ inline void tsplit(float x, short &hi, short &lo) {
    union { float f; unsigned u; } c; c.f = x;
    hi = (short)(c.u >> 16);
    union { unsigned u; float f; } h; h.u = c.u & 0xFFFF0000u;
    union { float f; unsigned u; } r; r.f = x - h.f;
    lo = (short)(r.u >> 16);
}

// Wave-visibility barrier: LDS writes drained (lgkmcnt), but global loads
// (private dest regs) intentionally left in flight -- no vmcnt drain.
__device__ inline void lds_barrier() {
    __builtin_amdgcn_sched_barrier(0);
    asm volatile("s_waitcnt lgkmcnt(0)" ::: "memory");
    __builtin_amdgcn_s_barrier();
    __builtin_amdgcn_sched_barrier(0);
}

__global__ __launch_bounds__(256, 2) void stickbreak_mfma(
    const float* __restrict__ Qg, const float* __restrict__ Kg,
    const float* __restrict__ Vg, float* __restrict__ Og)
{
    __shared__ __align__(16) short Kh[2][64 * PITCH];
    __shared__ __align__(16) short Kl[2][64 * PITCH];
    __shared__ __align__(16) short Vt[2][64 * PITCH];   // V transposed: Vt[d][j]
    __shared__ __align__(16) short Ws[64 * PITCH];      // W strip, [i][j] (intra-wave use)

    const int t = threadIdx.x;
    const int n = blockIdx.x;                 // 0..511
    // n&7 fastest -> all 16 q-tiles of one head share an XCD slot (K/V L2 reuse).
    const int bh = (n & 7) + 8 * (n >> 7);    // 0..31
    const int qr = (n >> 3) & 15;
    const int qt = (n >> 8) ? (15 - qr) : qr; // complementary pairing c <-> c+256

    const size_t hbase = (size_t)bh * 1024 * 64;
    const float* qp = Qg + hbase + (size_t)qt * 64 * 64;
    const float* kp = Kg + hbase;
    const float* vp = Vg + hbase;
    float*       op = Og + hbase + (size_t)qt * 64 * 64;

    const int lane = t & 63;
    const int wv   = t >> 6;      // wave 0..3 -> q-rows [16wv, 16wv+16)
    const int l16  = lane & 15;
    const int q4   = lane >> 4;   // quad 0..3

    // staging maps (K: 16 floats/thread; V transpose: 4x4 register block)
    const int srow = t >> 2;            // 0..63
    const int scol = (t & 3) << 4;      // 0/16/32/48
    const int vj   = (t & 15) << 2;
    const int vd   = (t >> 4) << 2;

    // ---- Q fragments straight to registers (loop-invariant) ----
    short8 qfh[2], qfl[2];
    {
        const float* qrow = qp + (16 * wv + l16) * 64;
        #pragma unroll
        for (int ks = 0; ks < 2; ++ks) {
            const int base = 32 * ks + 8 * q4;
            const float4 f0 = *(const float4*)(qrow + base);
            const float4 f1 = *(const float4*)(qrow + base + 4);
            float a[8] = {f0.x, f0.y, f0.z, f0.w, f1.x, f1.y, f1.z, f1.w};
            #pragma unroll
            for (int j = 0; j < 8; ++j) {
                short hi, lo;
                tsplit(a[j], hi, lo);
                qfh[ks][j] = hi;
                qfl[ks][j] = lo;
            }
        }
    }

    f32x4 Oacc[4];
    #pragma unroll
    for (int i = 0; i < 4; ++i) Oacc[i] = (f32x4){0.f, 0.f, 0.f, 0.f};
    float Prow = 1.f;    // carried suffix PRODUCT for row 16wv+l16 (replicated over q4)

    float4 kreg[4], vreg[4];

    // issue global loads for K/V tile tt into kreg/vreg (non-blocking)
    auto prefetch_tile = [&](int tt) {
        const float* ksrc = kp + (size_t)tt * 4096 + srow * 64 + scol;
        const float* vsrc = vp + (size_t)tt * 4096;
        #pragma unroll
        for (int i = 0; i < 4; ++i) kreg[i] = *(const float4*)(ksrc + 4 * i);
        #pragma unroll
        for (int r = 0; r < 4; ++r) vreg[r] = *(const float4*)(vsrc + (vj + r) * 64 + vd);
    };

    // convert kreg/vreg and store into LDS buffer nb
    auto stage_tile = [&](int nb) {
        short8 h0, h1, l0, l1;
        #pragma unroll
        for (int i = 0; i < 4; ++i) {
            float a[4] = {kreg[i].x, kreg[i].y, kreg[i].z, kreg[i].w};
            #pragma unroll
            for (int j = 0; j < 4; ++j) {
                short hi, lo;
                tsplit(a[j], hi, lo);
                const int idx = 4 * i + j;
                if (idx < 8) { h0[idx] = hi; l0[idx] = lo; }
                else         { h1[idx - 8] = hi; l1[idx - 8] = lo; }
            }
        }
        *(short8*)&Kh[nb][srow * PITCH + scol]     = h0;
        *(short8*)&Kh[nb][srow * PITCH + scol + 8] = h1;
        *(short8*)&Kl[nb][srow * PITCH + scol]     = l0;
        *(short8*)&Kl[nb][srow * PITCH + scol + 8] = l1;
        #pragma unroll
        for (int x = 0; x < 4; ++x) {
            float rr[4] = { x == 0 ? vreg[0].x : x == 1 ? vreg[0].y : x == 2 ? vreg[0].z : vreg[0].w,
                            x == 0 ? vreg[1].x : x == 1 ? vreg[1].y : x == 2 ? vreg[1].z : vreg[1].w,
                            x == 0 ? vreg[2].x : x == 1 ? vreg[2].y : x == 2 ? vreg[2].z : vreg[2].w,
                            x == 0 ? vreg[3].x : x == 1 ? vreg[3].y : x == 2 ? vreg[3].z : vreg[3].w };
            short4v w4;
            #pragma unroll
            for (int r = 0; r < 4; ++r) w4[r] = bf16r(rr[r]);   // V stays RNE
            *(short4v*)&Vt[nb][(vd + x) * PITCH + vj] = w4;
        }
    };

    // ---- prologue: load + stage tile qt into buf 0, start prefetch of qt-1 ----
    prefetch_tile(qt);
    stage_tile(0);
    if (qt > 0) prefetch_tile(qt - 1);
    lds_barrier();

    for (int kt = qt; kt >= 0; --kt) {
        const int cur = (qt - kt) & 1;

        // ---- GEMM1: S^T = K Q^T (split precision, 3 MFMAs per frag pair) ----
        // D[m=j][n=i]: col i = l16, row j = 16nt + 4q4 + reg.
        f32x4 Sacc[4];
        #pragma unroll
        for (int i = 0; i < 4; ++i) Sacc[i] = (f32x4){0.f, 0.f, 0.f, 0.f};
        #pragma unroll
        for (int ks = 0; ks < 2; ++ks) {
            #pragma unroll
            for (int nt = 0; nt < 4; ++nt) {
                const short8 ah = *(const short8*)&Kh[cur][(16 * nt + l16) * PITCH + 32 * ks + 8 * q4];
                const short8 al = *(const short8*)&Kl[cur][(16 * nt + l16) * PITCH + 32 * ks + 8 * q4];
                Sacc[nt] = __builtin_amdgcn_mfma_f32_16x16x32_bf16(ah, qfh[ks], Sacc[nt], 0, 0, 0);
                Sacc[nt] = __builtin_amdgcn_mfma_f32_16x16x32_bf16(al, qfh[ks], Sacc[nt], 0, 0, 0);
                Sacc[nt] = __builtin_amdgcn_mfma_f32_16x16x32_bf16(ah, qfl[ks], Sacc[nt], 0, 0, 0);
            }
        }

        // ---- elementwise + suffix scan, PRODUCT space ----
        // lane owns row i=16wv+l16, j = 16nt+4q4+reg.
        //   e = exp2(l*C) = exp(l/8); b = rcp(1+e) = sigmoid(-l); z = e*b = sigmoid(l)
        //   w[j] = z_j * prod_{j'=j..i} b_j'   (inclusive; b_j appears twice, as in ref)
        const bool diag = (kt == qt);
        const int irow = 16 * wv + l16;          // row within 64-row q-tile
        const float C = 0.180336880f;            // 0.125 * log2(e)
        float zp[4][4];                          // z * in-run inclusive suffix product
        float sR[4];                             // run total products
        #pragma unroll
        for (int nt = 0; nt < 4; ++nt) {
            float b[4], zz[4];
            #pragma unroll
            for (int reg = 0; reg < 4; ++reg) {
                float l2 = Sacc[nt][reg] * C;
                if (diag && (16 * nt + 4 * q4 + reg > irow)) l2 = -1e30f;  // mask sentinel
                l2 = fminf(l2, 80.f);                     // exp2 overflow guard (inf*0=NaN)
                const float e  = __builtin_amdgcn_exp2f(l2);
                const float bb = __builtin_amdgcn_rcpf(1.f + e);
                b[reg] = bb;
                zz[reg] = e * bb;
            }
            const float p3 = b[3];
            const float p2 = b[2] * p3;
            const float p1 = b[1] * p2;
            const float p0 = b[0] * p1;          // inclusive suffix product within run
            zp[nt][0] = zz[0] * p0;
            zp[nt][1] = zz[1] * p1;
            zp[nt][2] = zz[2] * p2;
            zp[nt][3] = zz[3] * p3;
            sR[nt] = p0;
        }
        // cross-lane inclusive suffix PRODUCT over q4 (stride-16 lanes), then over nt
        float ex4[4], Tn[4];
        #pragma unroll
        for (int nt = 0; nt < 4; ++nt) {
            float g = sR[nt];
            float u = __shfl_down(g, 16, 64); if (q4 < 3) g *= u;
            u = __shfl_down(g, 32, 64);       if (q4 < 2) g *= u;
            const float x = __shfl_down(g, 16, 64);   // inclusive product at q4+1
            ex4[nt] = (q4 == 3) ? 1.f : x;            // exclusive: prod over q4' > q4
            Tn[nt]  = __shfl(g, l16, 64);             // nt total (from q4=0 lane of same i)
        }
        const float TSa[4] = { Tn[1] * Tn[2] * Tn[3], Tn[2] * Tn[3], Tn[3], 1.f };
        #pragma unroll
        for (int nt = 0; nt < 4; ++nt) {
            const float cross = ex4[nt] * TSa[nt] * Prow;
            short4v w4;
            #pragma unroll
            for (int reg = 0; reg < 4; ++reg)
                w4[reg] = bf16r(zp[nt][reg] * cross);
            *(short4v*)&Ws[irow * PITCH + 16 * nt + 4 * q4] = w4;
        }
        Prow *= TSa[0] * Tn[0];

        // ---- GEMM2: O += W V  (Ws rows are wave-local; compiler inserts the
        //      lgkmcnt wait for the intra-wave LDS RAW -- no barrier needed) ----
        #pragma unroll
        for (int ks = 0; ks < 2; ++ks) {
            const short8 wa = *(const short8*)&Ws[(16 * wv + l16) * PITCH + 32 * ks + 8 * q4];
            #pragma unroll
            for (int dt = 0; dt < 4; ++dt) {
                const short8 vb = *(const short8*)&Vt[cur][(16 * dt + l16) * PITCH + 32 * ks + 8 * q4];
                Oacc[dt] = __builtin_amdgcn_mfma_f32_16x16x32_bf16(wa, vb, Oacc[dt], 0, 0, 0);
            }
        }

        // ---- stage next tile into the other buffer, prefetch the one after ----
        if (kt > 0) {
            stage_tile(cur ^ 1);                 // consumes kreg/vreg (tile kt-1)
            if (kt > 1) prefetch_tile(kt - 2);   // loads fly across the barrier
            lds_barrier();                       // lgkm only: staging visible, reads drained
        }
    }

    // ---- epilogue: C-layout scatter to global (fp32) ----
    #pragma unroll
    for (int dt = 0; dt < 4; ++dt)
        #pragma unroll
        for (int r = 0; r < 4; ++r)
            op[(16 * wv + 4 * q4 + r) * 64 + 16 * dt + l16] = Oacc[dt][r];
}

extern "C" void kernel_launch(void* const* d_in, const int* in_sizes, int n_in,
                              void* d_out, int out_size, void* d_ws, size_t ws_size,
                              hipStream_t stream) {
    const float* q = (const float*)d_in[0];
    const float* k = (const float*)d_in[1];
    const float* v = (const float*)d_in[2];
    float* out = (float*)d_out;
    stickbreak_mfma<<<dim3(512), dim3(256), 0, stream>>>(q, k, v, out);
}